// Round 6
// baseline (596.196 us; speedup 1.0000x reference)
//
#include <hip/hip_runtime.h>
#include <hip/hip_fp16.h>
#include <stdint.h>

// GCN: 2×(GCNConv + ReLU) + linear head.  CSR (by dst) built once per launch.
// Linearity: agg(x@W) == agg(x)@W, so layer 1 aggregates raw 22-dim x.
// Round 5 (resubmit after acquisition timeout): 16B/lane (dwordx4) gathers.
// agg2: 8 edge-slots x 8 feature-groups, 32 edges in flight/wave.
// agg1: 16 slots x 4 groups, 64 edges in flight.
// Slot reduction via shfl_xor; transforms via fully-unrolled register shuffles.

static constexpr int FIN = 22;
static constexpr int NWIN = 8;   // = XCD count
static constexpr int XW = 16;    // xs row stride in __half2 words (64 B)

struct H8 { __half2 h[4]; };     // 16 B gather payload

__global__ void k_zero(int* cnt, int N) {
  int i = blockIdx.x * blockDim.x + threadIdx.x;
  int stride = gridDim.x * blockDim.x;
  for (; i < N; i += stride) cnt[i] = 0;
}

// Detect int64 vs int32 edge_index: sample 64 odd 32-bit words; all-zero => int64.
__global__ void k_detect(const unsigned int* w, int E, int* flag) {
  int t = threadIdx.x;
  size_t pos = 2ull * ((size_t)t * (size_t)(E / 64)) + 1ull;
  unsigned v = w[pos];
  unsigned long long b = __ballot(v != 0u);
  if (t == 0) *flag = (b == 0ull) ? 1 : 0;
}

__device__ __forceinline__ int load_idx(const void* ei, size_t i, int is64) {
  return is64 ? (int)((const long long*)ei)[i] : ((const int*)ei)[i];
}

// count in-degree + compact edge list to int32.
__global__ void k_count(const void* ei, const int* __restrict__ flag, int* cnt,
                        int* src32, int* dst32, int E) {
  int is64 = *flag;
  int i = blockIdx.x * blockDim.x + threadIdx.x;
  int stride = gridDim.x * blockDim.x;
  for (; i < E; i += stride) {
    int s = load_idx(ei, (size_t)i, is64);
    int d = load_idx(ei, (size_t)E + (size_t)i, is64);
    src32[i] = s;
    dst32[i] = d;
    atomicAdd(&cnt[d], 1);
  }
}

// ---- parallel exclusive scan of cnt (3 kernels) ----
__global__ void k_scan1(const int* __restrict__ cnt, int* partial, int N) {
  __shared__ int sh[256];
  int b = blockIdx.x, t = threadIdx.x;
  int i0 = b * 1024 + t * 4;
  int s = 0;
#pragma unroll
  for (int k = 0; k < 4; ++k) {
    int i = i0 + k;
    if (i < N) s += cnt[i];
  }
  sh[t] = s;
  __syncthreads();
  for (int off = 128; off > 0; off >>= 1) {
    if (t < off) sh[t] += sh[t + off];
    __syncthreads();
  }
  if (t == 0) partial[b] = sh[0];
}

__global__ void k_scan2(int* partial, int nb) {
  __shared__ int sh[128];
  int t = threadIdx.x;
  int v = (t < nb) ? partial[t] : 0;
  sh[t] = v;
  __syncthreads();
  for (int off = 1; off < 128; off <<= 1) {
    int u = (t >= off) ? sh[t - off] : 0;
    __syncthreads();
    sh[t] += u;
    __syncthreads();
  }
  if (t < nb) partial[t] = sh[t] - v;
}

__global__ void k_scan3(const int* __restrict__ cnt, const int* __restrict__ base,
                        int* row_ptr, int* fillc, float* dinv, int N) {
  __shared__ int sh[256];
  int b = blockIdx.x, t = threadIdx.x;
  int i0 = b * 1024 + t * 4;
  int c[4];
  int s = 0;
#pragma unroll
  for (int k = 0; k < 4; ++k) {
    int i = i0 + k;
    c[k] = (i < N) ? cnt[i] : 0;
    s += c[k];
  }
  sh[t] = s;
  __syncthreads();
  int v = s;
  for (int off = 1; off < 256; off <<= 1) {
    int u = (t >= off) ? sh[t - off] : 0;
    __syncthreads();
    sh[t] += u;
    __syncthreads();
  }
  int excl = sh[t] - v + base[b];
#pragma unroll
  for (int k = 0; k < 4; ++k) {
    int i = i0 + k;
    if (i < N) {
      row_ptr[i] = excl;
      fillc[i] = excl;
      dinv[i] = rsqrtf((float)(c[k] + 1));
      excl += c[k];
    }
  }
  if (b == gridDim.x - 1 && t == 255) row_ptr[N] = excl;
}

// XCD-windowed fill over compacted int32 edges.
__global__ void k_fill_win(const int* __restrict__ src32, const int* __restrict__ dst32,
                           int* fillc, int* colv, int E, int winsize) {
  int win = blockIdx.x % NWIN;
  int lo = win * winsize, hi = lo + winsize;
  int nb = gridDim.x / NWIN;
  int bw = blockIdx.x / NWIN;
  long long i = (long long)bw * blockDim.x + threadIdx.x;
  long long stride = (long long)nb * blockDim.x;
  for (; i < E; i += stride) {
    int d = dst32[i];
    if (d >= lo && d < hi) {
      int s = src32[i];
      int p = atomicAdd(&fillc[d], 1);
      colv[p] = s;
    }
  }
}

// xs2[i][w] = half2( x[i][2w]*dinv[i], x[i][2w+1]*dinv[i] ), padded to XW words (64B row).
__global__ void k_xs(const float* __restrict__ x, const float* __restrict__ dinv,
                     __half2* __restrict__ xs2, int N) {
  int i = blockIdx.x * blockDim.x + threadIdx.x;
  int stride = gridDim.x * blockDim.x;
  int total = N * XW;
  for (; i < total; i += stride) {
    int node = i >> 4, w = i & (XW - 1);
    float a = 0.f, b = 0.f;
    if (2 * w < FIN) {
      float di = dinv[node];
      a = x[(size_t)node * FIN + 2 * w] * di;
      b = x[(size_t)node * FIN + 2 * w + 1] * di;   // FIN even, both valid
    }
    xs2[i] = __floats2half2_rn(a, b);
  }
}

// Layer 1: aggregate 22-dim xs (64B rows), transform W1, relu -> s2 (fp16, 128B rows).
// 16 edge-slots x 4 feature-groups; 4 groups unrolled = 64 edges in flight.
__global__ void k_agg1(const H8* __restrict__ xs4, const int* __restrict__ row_ptr,
                       const int* __restrict__ colv, const float* __restrict__ dinv,
                       const float* __restrict__ W1, const float* __restrict__ b1,
                       __half* __restrict__ s2h, int N) {
  __shared__ float w1[FIN * 64];
  int t = threadIdx.x;
  for (int i = t; i < FIN * 64; i += blockDim.x) w1[i] = W1[i];
  __syncthreads();
  int wib = t >> 6, lane = t & 63;
  int node = blockIdx.x * 4 + wib;
  if (node >= N) return;
  int eslot = lane >> 2, fg = lane & 3;
  int start = row_ptr[node], end = row_ptr[node + 1];
  float ax[4] = {0.f, 0.f, 0.f, 0.f}, ay[4] = {0.f, 0.f, 0.f, 0.f};
  for (int pos = start; pos < end; pos += 64) {
#pragma unroll
    for (int g = 0; g < 4; ++g) {
      int e = pos + g * 16 + eslot;
      int a = colv[min(e, end - 1)];
      H8 v = xs4[(size_t)a * 4 + fg];
      float msk = (e < end) ? 1.f : 0.f;
#pragma unroll
      for (int w = 0; w < 4; ++w) {
        float2 f = __half22float2(v.h[w]);
        ax[w] += msk * f.x;
        ay[w] += msk * f.y;
      }
    }
  }
  // reduce across the 16 edge-slots (lane bits 2..5)
#pragma unroll
  for (int m = 4; m <= 32; m <<= 1) {
#pragma unroll
    for (int w = 0; w < 4; ++w) {
      ax[w] += __shfl_xor(ax[w], m);
      ay[w] += __shfl_xor(ay[w], m);
    }
  }
  float di = dinv[node];
  H8 sv = xs4[(size_t)node * 4 + fg];
  float tt[8];
#pragma unroll
  for (int w = 0; w < 4; ++w) {
    float2 f = __half22float2(sv.h[w]);
    tt[2 * w]     = di * (ax[w] + f.x);   // t1[8*fg + 2w]
    tt[2 * w + 1] = di * (ay[w] + f.y);   // t1[8*fg + 2w+1]
  }
  float o = 0.f;
#pragma unroll
  for (int k = 0; k < FIN; ++k) {
    float tk = __shfl(tt[k & 7], k >> 3);  // t1[k] lives on lane (k>>3) (fg==k>>3)
    o += tk * w1[k * 64 + lane];
  }
  float h = fmaxf(o + b1[lane], 0.f);
  s2h[(size_t)node * 64 + lane] = __float2half(h * di);
}

// Layer 2 + head: aggregate 64-dim fp16 s2 (128B rows), transform W2, relu, dot Wf.
// 8 edge-slots x 8 feature-groups; 4 groups unrolled = 32 edges in flight.
__global__ void k_agg2(const H8* __restrict__ s2q, const int* __restrict__ row_ptr,
                       const int* __restrict__ colv, const float* __restrict__ dinv,
                       const float* __restrict__ W2, const float* __restrict__ b2,
                       const float* __restrict__ Wf, const float* __restrict__ bf,
                       float* __restrict__ out, int N) {
  __shared__ float w2[64 * 64];
  int t = threadIdx.x;
  for (int i = t; i < 64 * 64; i += blockDim.x) w2[i] = W2[i];
  __syncthreads();
  int wib = t >> 6, lane = t & 63;
  int node = blockIdx.x * 4 + wib;
  if (node >= N) return;
  int eslot = lane >> 3, fg = lane & 7;
  int start = row_ptr[node], end = row_ptr[node + 1];
  float ax[4] = {0.f, 0.f, 0.f, 0.f}, ay[4] = {0.f, 0.f, 0.f, 0.f};
  for (int pos = start; pos < end; pos += 32) {
#pragma unroll
    for (int g = 0; g < 4; ++g) {
      int e = pos + g * 8 + eslot;
      int a = colv[min(e, end - 1)];
      H8 v = s2q[(size_t)a * 8 + fg];
      float msk = (e < end) ? 1.f : 0.f;
#pragma unroll
      for (int w = 0; w < 4; ++w) {
        float2 f = __half22float2(v.h[w]);
        ax[w] += msk * f.x;
        ay[w] += msk * f.y;
      }
    }
  }
  // reduce across the 8 edge-slots (lane bits 3..5)
#pragma unroll
  for (int m = 8; m <= 32; m <<= 1) {
#pragma unroll
    for (int w = 0; w < 4; ++w) {
      ax[w] += __shfl_xor(ax[w], m);
      ay[w] += __shfl_xor(ay[w], m);
    }
  }
  float di = dinv[node];
  H8 sv = s2q[(size_t)node * 8 + fg];
  float tt[8];
#pragma unroll
  for (int w = 0; w < 4; ++w) {
    float2 f = __half22float2(sv.h[w]);
    tt[2 * w]     = di * (ax[w] + f.x);   // t2[8*fg + 2w]
    tt[2 * w + 1] = di * (ay[w] + f.y);
  }
  float o = 0.f;
#pragma unroll
  for (int k = 0; k < 64; ++k) {
    float tk = __shfl(tt[k & 7], k >> 3);  // t2[k] lives on lane (k>>3)
    o += tk * w2[k * 64 + lane];
  }
  float h = fmaxf(o + b2[lane], 0.f);
  float v = h * Wf[lane];
#pragma unroll
  for (int off = 32; off > 0; off >>= 1) v += __shfl_down(v, off);
  if (lane == 0) out[node] = v + bf[0];
}

extern "C" void kernel_launch(void* const* d_in, const int* in_sizes, int n_in,
                              void* d_out, int out_size, void* d_ws, size_t ws_size,
                              hipStream_t stream) {
  const float* x  = (const float*)d_in[0];
  const void*  ei = d_in[1];
  const float* W1 = (const float*)d_in[2];
  const float* b1 = (const float*)d_in[3];
  const float* W2 = (const float*)d_in[4];
  const float* b2 = (const float*)d_in[5];
  const float* Wf = (const float*)d_in[6];
  const float* bf = (const float*)d_in[7];
  int N = in_sizes[0] / FIN;
  int E = in_sizes[1] / 2;
  float* outp = (float*)d_out;

  char* p = (char*)d_ws;
  auto alloc = [&](size_t bytes) {
    void* r = (void*)p;
    p += (bytes + 255) & ~(size_t)255;
    return r;
  };
  int*     cnt     = (int*)alloc((size_t)N * 4);
  int*     row_ptr = (int*)alloc(((size_t)N + 1) * 4);
  int*     fillc   = (int*)alloc((size_t)N * 4);
  float*   dinv    = (float*)alloc((size_t)N * 4);
  int*     flag    = (int*)alloc(256);
  int*     partial = (int*)alloc(1024);
  int*     colv    = (int*)alloc((size_t)E * 4);
  int*     src32   = (int*)alloc((size_t)E * 4);
  int*     dst32   = (int*)alloc((size_t)E * 4);
  __half2* xs2     = (__half2*)alloc((size_t)N * XW * 4);
  __half*  s2h     = (__half*)alloc((size_t)N * 64 * 2);
  (void)ws_size; (void)n_in; (void)out_size;

  int egrid = min((E + 255) / 256, 12544);
  int ngrid = (N + 255) / 256;
  int sgrid = (N + 1023) / 1024;
  int xgrid = min((N * XW + 255) / 256, 8704);
  int wgrid = (N + 3) / 4;
  int winsize = (N + NWIN - 1) / NWIN;

  k_zero    <<<ngrid, 256, 0, stream>>>(cnt, N);
  k_detect  <<<1, 64, 0, stream>>>((const unsigned int*)ei, E, flag);
  k_count   <<<egrid, 256, 0, stream>>>(ei, flag, cnt, src32, dst32, E);
  k_scan1   <<<sgrid, 256, 0, stream>>>(cnt, partial, N);
  k_scan2   <<<1, 128, 0, stream>>>(partial, sgrid);
  k_scan3   <<<sgrid, 256, 0, stream>>>(cnt, partial, row_ptr, fillc, dinv, N);
  k_fill_win<<<2048, 256, 0, stream>>>(src32, dst32, fillc, colv, E, winsize);
  k_xs      <<<xgrid, 256, 0, stream>>>(x, dinv, xs2, N);
  k_agg1    <<<wgrid, 256, 0, stream>>>((const H8*)xs2, row_ptr, colv, dinv, W1, b1, s2h, N);
  k_agg2    <<<wgrid, 256, 0, stream>>>((const H8*)s2h, row_ptr, colv, dinv,
                                        W2, b2, Wf, bf, outp, N);
}